// Round 2
// baseline (184.800 us; speedup 1.0000x reference)
//
#include <hip/hip_runtime.h>
#include <math.h>

#define T_   2048
#define NB_  64
#define NU_  8
#define NY_  8
#define NH_  256
#define H2_  128
#define CCH  64      // number of chunks
#define LCH  32      // chunk length = T_/CCH

static const float PI_HALF = 1.5707963267948966f;

typedef _Float16 half8  __attribute__((ext_vector_type(8)));
typedef __fp16   fp16x2 __attribute__((ext_vector_type(2)));
typedef float    f32x4  __attribute__((ext_vector_type(4)));

// ws layout (bytes):
//   done  int                            @ 8
//   M     u32[256][128]                  @ 16384    128 KB
//   c_buf f32[k][b][pair][2]             @ 147456   4 MB
//   initT u32[k][b][128]                 @ 4341760  2 MB
#define OFF_CNT   8
#define OFF_M     16384
#define OFF_CBUF  147456
#define OFF_INIT  4341760

// ---------------- kernel 1: M-precompute blocks + scan/projection blocks -----
__global__ __launch_bounds__(128) void k_scanM(
    const float* __restrict__ U, const float* __restrict__ bx2y,
    const float* __restrict__ lr, const float* __restrict__ li,
    const float* __restrict__ B, const float* __restrict__ mult,
    const float* __restrict__ Wx2y,
    char* __restrict__ ws, float* __restrict__ c_buf,
    float* __restrict__ Y)
{
    const int bi  = blockIdx.x;
    const int tid = threadIdx.x;

    if (bi == 0 && tid == 0) {
        // zero the prefix/corr handshake counter (stream-ordered before k_pc)
        *(volatile int*)(ws + OFF_CNT) = 0;
    }

    if (bi < 256) {
        // ---- M[R = dlt*8+y][m] row, one thread per pair-column ----
        uint32_t* M32 = (uint32_t*)(ws + OFF_M);
        const int R = bi, dlt = R >> 3, y = R & 7;
        const int h = tid;
        const float e = (float)(dlt + 1);
        float r  = expf(-e * fabsf(lr[h]));
        float an = e * PI_HALF * li[h];
        float c = r * cosf(an), sn = r * sinf(an);
        float W1 = Wx2y[y*NH_ + h];
        float W2 = Wx2y[y*NH_ + h + H2_];
        float Mre = fmaf(W1, c,  W2 * sn);
        float Mim = fmaf(W2, c, -W1 * sn);
        union { fp16x2 h2; uint32_t u32; } pk;
        pk.h2 = __builtin_amdgcn_cvt_pkrtz(Mre, Mim);
        M32[R*128 + h] = pk.u32;
        return;
    }

    // ---- scan + K-split MFMA projection ----
    const int kb  = bi - 256;
    const int k   = kb >> 6;
    const int b   = kb & 63;
    const int h   = tid;
    const int w   = tid >> 6;
    const int l   = tid & 63;
    const int row = l & 15;
    const int kg  = (l >> 4) & 3;

    float4 lam;
    {
        float a_ = fabsf(lr[h]);
        float r_ = expf(-a_);
        float th = PI_HALF * li[h];
        float re = r_ * cosf(th), im = r_ * sinf(th);
        lam = make_float4(re, im, -im, re);
    }
    float B1[NU_], B2[NU_];
    {
        float s1 = expf(mult[h]), s2 = expf(mult[h + H2_]);
        const float4* bp1 = (const float4*)(B + h*NU_);
        const float4* bp2 = (const float4*)(B + (h + H2_)*NU_);
        float4 a0 = bp1[0], a1 = bp1[1], a2 = bp2[0], a3 = bp2[1];
        B1[0]=a0.x*s1; B1[1]=a0.y*s1; B1[2]=a0.z*s1; B1[3]=a0.w*s1;
        B1[4]=a1.x*s1; B1[5]=a1.y*s1; B1[6]=a1.z*s1; B1[7]=a1.w*s1;
        B2[0]=a2.x*s2; B2[1]=a2.y*s2; B2[2]=a2.z*s2; B2[3]=a2.w*s2;
        B2[4]=a3.x*s2; B2[5]=a3.y*s2; B2[6]=a3.z*s2; B2[7]=a3.w*s2;
    }
    half8 wf[4];
    #pragma unroll
    for (int q2 = 0; q2 < 4; q2++) {
        const int q = 4*w + q2;
        union { uint32_t u[4]; half8 h8; } fu;
        if (row < 8) {
            const float4 wa = *(const float4*)(Wx2y + row*NH_ + q*16 + kg*4);
            const float4 wb = *(const float4*)(Wx2y + row*NH_ + q*16 + kg*4 + H2_);
            union { fp16x2 h2; uint32_t u32; } p;
            p.h2 = __builtin_amdgcn_cvt_pkrtz(wa.x, wb.x); fu.u[0] = p.u32;
            p.h2 = __builtin_amdgcn_cvt_pkrtz(wa.y, wb.y); fu.u[1] = p.u32;
            p.h2 = __builtin_amdgcn_cvt_pkrtz(wa.z, wb.z); fu.u[2] = p.u32;
            p.h2 = __builtin_amdgcn_cvt_pkrtz(wa.w, wb.w); fu.u[3] = p.u32;
        } else {
            fu.u[0]=0; fu.u[1]=0; fu.u[2]=0; fu.u[3]=0;
        }
        wf[q2] = fu.h8;
    }
    const float bias = bx2y[tid & 7];

    __shared__ float    uS[LCH*NU_];    // 1 KB
    __shared__ _Float16 xS[16*256];     // 8 KB
    __shared__ float    pS[4*132];
    uint32_t* xS32 = (uint32_t*)xS;

    if (tid < 64) {
        ((float4*)uS)[tid] =
            *(const float4*)(U + ((size_t)(k*LCH + (tid>>1))*NB_ + b)*NU_ + (tid&1)*4);
    }
    __syncthreads();

    float x1 = 0.f, x2 = 0.f;
    const int g = h >> 2;

    for (int s = 0; s < 2; s++) {
        #pragma unroll 4
        for (int t16 = 0; t16 < 16; t16++) {
            const int t = s*16 + t16;
            float4 u0 = ((const float4*)uS)[2*t+0];
            float4 u1 = ((const float4*)uS)[2*t+1];
            float u[NU_] = {u0.x,u0.y,u0.z,u0.w,u1.x,u1.y,u1.z,u1.w};
            float bu1=0.f, bu2=0.f;
            #pragma unroll
            for (int i = 0; i < NU_; i++) {
                bu1 = fmaf(u[i], B1[i], bu1);
                bu2 = fmaf(u[i], B2[i], bu2);
            }
            float n1 = fmaf(lam.x, x1, fmaf(lam.z, x2, bu1));
            float n2 = fmaf(lam.y, x1, fmaf(lam.w, x2, bu2));
            x1 = n1; x2 = n2;

            union { fp16x2 h2; uint32_t u32; } pk;
            pk.h2 = __builtin_amdgcn_cvt_pkrtz(x1, x2);
            xS32[t16*128 + ((g ^ t16) & 31)*4 + (h & 3)] = pk.u32;
        }
        __syncthreads();

        f32x4 acc = {0.f,0.f,0.f,0.f};
        #pragma unroll
        for (int q2 = 0; q2 < 4; q2++) {
            const int q = 4*w + q2;
            const int p = ((q << 2) + kg) ^ row;
            const half8* ap = (const half8*)(xS + (row << 8) + (p << 3));
            acc = __builtin_amdgcn_mfma_f32_16x16x32_f16(*ap, wf[q2], acc, 0, 0, 0);
        }
        #pragma unroll
        for (int r = 0; r < 4; r++) pS[r*132 + w*64 + l] = acc[r];
        __syncthreads();

        {
            const int t  = tid >> 3, y = tid & 7;
            const int ls = ((t >> 2) << 4) + y;
            const int rg = t & 3;
            float sum = pS[rg*132 + ls] + pS[rg*132 + 64 + ls];
            Y[((size_t)(k*LCH + s*16 + t)*NB_ + b)*NY_ + y] = sum + bias;
        }
    }

    *(float2*)(c_buf + (size_t)(k*NB_ + b)*(H2_*2) + 2*h) = make_float2(x1, x2);
}

// ---------------- kernel 2: fused segmented-prefix + correction GEMM ---------
// 512 blocks x 256 threads, co-resident via __launch_bounds__(256,2)
// (2 blocks/CU x 256 CUs = 512 = grid; LDS 19 KB/block, VGPR <= 256).
// Blocks 0..255: segmented prefix for 32 chains x 8 segments each.
// All blocks: spin on agent-scope counter (zeroed by k_scanM), then corr GEMM.
__global__ __launch_bounds__(256, 2) void k_pc(
    const float* __restrict__ y0, const float* __restrict__ Wy2x,
    const float* __restrict__ by2x,
    const float* __restrict__ lr, const float* __restrict__ li,
    const float* __restrict__ c_buf, const _Float16* __restrict__ M,
    uint32_t* __restrict__ initT, float* __restrict__ Y,
    int* __restrict__ done)
{
    const int bi  = blockIdx.x;
    const int tid = threadIdx.x;

    __shared__ float2   Pseg[32][8];     // 2 KB (prefix phase)
    __shared__ _Float16 bS[32*264];      // 16.5 KB (corr phase)

    if (bi < 256) {
        // ---- segmented prefix: chain = (b,h), 8 segments of 8 chunks ----
        const int chain = (bi << 5) + (tid >> 3);   // 0..8191
        const int seg   = tid & 7;                  // 0..7
        const int b = chain >> 7, h = chain & 127;

        const float a_  = fabsf(lr[h]);
        const float liv = li[h];
        const float rL  = expf(-(float)LCH * a_);
        const float thL = (float)LCH * PI_HALF * liv;
        const float reL = rL * cosf(thL), imL = rL * sinf(thL);
        const float r8  = expf(-(float)(8*LCH) * a_);
        const float th8 = (float)(8*LCH) * PI_HALF * liv;
        const float re8 = r8 * cosf(th8), im8 = r8 * sinf(th8);

        // pass 1: zero-init partial over this segment's 8 chunks
        float p1 = 0.f, p2 = 0.f;
        #pragma unroll
        for (int i = 0; i < 8; i++) {
            const int k = (seg << 3) + i;
            float2 c = *(const float2*)(c_buf + (size_t)k*16384 + b*256 + 2*h);
            float n1 = fmaf(reL, p1, fmaf(-imL, p2, c.x));
            float n2 = fmaf(imL, p1, fmaf( reL, p2, c.y));
            p1 = n1; p2 = n2;
        }
        Pseg[tid >> 3][seg] = make_float2(p1, p2);

        // true init x0 (redundant per segment-thread; 16 FMAs)
        float x1 = by2x[h], x2 = by2x[h + H2_];
        #pragma unroll
        for (int y = 0; y < NY_; y++) {
            float yy = y0[b*NY_ + y];
            x1 = fmaf(yy, Wy2x[h*NY_ + y],        x1);
            x2 = fmaf(yy, Wy2x[(h+H2_)*NY_ + y],  x2);
        }
        __syncthreads();

        // combine: X_seg = A8*X_{seg-1} + P_{seg-1}, predicated serial walk
        #pragma unroll
        for (int j = 0; j < 7; j++) {
            if (j < seg) {
                float2 Pj = Pseg[tid >> 3][j];
                float n1 = fmaf(re8, x1, fmaf(-im8, x2, Pj.x));
                float n2 = fmaf(im8, x1, fmaf( re8, x2, Pj.y));
                x1 = n1; x2 = n2;
            }
        }

        // pass 2: re-walk 8 chunks from true segment-start state
        #pragma unroll
        for (int i = 0; i < 8; i++) {
            const int k = (seg << 3) + i;
            union { fp16x2 hh; uint32_t u32; } pk;
            pk.hh = __builtin_amdgcn_cvt_pkrtz(x1, x2);
            initT[(size_t)k*8192 + b*128 + h] = pk.u32;
            float2 c = *(const float2*)(c_buf + (size_t)k*16384 + b*256 + 2*h);
            float n1 = fmaf(reL, x1, fmaf(-imL, x2, c.x));
            float n2 = fmaf(imL, x1, fmaf( reL, x2, c.y));
            x1 = n1; x2 = n2;
        }

        __threadfence();            // release initT writes (device scope)
        __syncthreads();
        if (tid == 0)
            __hip_atomic_fetch_add(done, 1, __ATOMIC_RELEASE,
                                   __HIP_MEMORY_SCOPE_AGENT);
    }

    // ---- wait until all 256 prefix blocks have released their initT ----
    if (tid == 0) {
        while (__hip_atomic_load(done, __ATOMIC_ACQUIRE,
                                 __HIP_MEMORY_SCOPE_AGENT) < 256)
            __builtin_amdgcn_s_sleep(4);
    }
    __syncthreads();
    __threadfence();                // acquire: make cross-XCD initT visible

    // ---- correction GEMM, Y += M @ init_k (identical math to old k_corr) ----
    const int k    = bi >> 3;
    const int half = (bi >> 2) & 1;
    const int rtg  = bi & 3;
    const int w    = tid >> 6, l = tid & 63;
    const int lane16 = l & 15, kg = l >> 4;

    {
        uint32_t* bS32 = (uint32_t*)bS;
        const int r = tid >> 3, seg = tid & 7;
        const uint32_t* src = initT + (size_t)k*8192 + (half*32 + r)*128 + seg*16;
        uint32_t* dst = bS32 + r*132 + seg*16;
        ((uint4*)dst)[0] = ((const uint4*)src)[0];
        ((uint4*)dst)[1] = ((const uint4*)src)[1];
        ((uint4*)dst)[2] = ((const uint4*)src)[2];
        ((uint4*)dst)[3] = ((const uint4*)src)[3];
    }
    __syncthreads();

    const int R0 = rtg*64 + w*16;
    half8 af[8];
    #pragma unroll
    for (int q = 0; q < 8; q++)
        af[q] = *(const half8*)(M + (size_t)(R0 + lane16)*256 + q*32 + kg*8);

    f32x4 acc0 = {0.f,0.f,0.f,0.f}, acc1 = {0.f,0.f,0.f,0.f};
    #pragma unroll
    for (int q = 0; q < 8; q++) {
        const half8* b0 = (const half8*)(bS + ( 0 + lane16)*264 + q*32 + kg*8);
        const half8* b1 = (const half8*)(bS + (16 + lane16)*264 + q*32 + kg*8);
        acc0 = __builtin_amdgcn_mfma_f32_16x16x32_f16(af[q], *b0, acc0, 0, 0, 0);
        acc1 = __builtin_amdgcn_mfma_f32_16x16x32_f16(af[q], *b1, acc1, 0, 0, 0);
    }

    const int t  = k*LCH + (R0 >> 3) + (kg >> 1);
    const int y0i = (kg & 1) * 4;
    float4* yp0 = (float4*)(Y + ((size_t)t*NB_ + half*32 +  0 + lane16)*NY_ + y0i);
    float4* yp1 = (float4*)(Y + ((size_t)t*NB_ + half*32 + 16 + lane16)*NY_ + y0i);
    float4 o0 = *yp0, o1 = *yp1;
    o0.x += acc0[0]; o0.y += acc0[1]; o0.z += acc0[2]; o0.w += acc0[3];
    o1.x += acc1[0]; o1.y += acc1[1]; o1.z += acc1[2]; o1.w += acc1[3];
    *yp0 = o0; *yp1 = o1;
}

extern "C" void kernel_launch(void* const* d_in, const int* in_sizes, int n_in,
                              void* d_out, int out_size, void* d_ws, size_t ws_size,
                              hipStream_t stream) {
    const float* y0   = (const float*)d_in[0];
    const float* U    = (const float*)d_in[1];
    const float* lr   = (const float*)d_in[2];
    const float* li   = (const float*)d_in[3];
    const float* B    = (const float*)d_in[4];
    const float* mult = (const float*)d_in[5];
    const float* Wy2x = (const float*)d_in[6];
    const float* by2x = (const float*)d_in[7];
    const float* Wx2y = (const float*)d_in[8];
    const float* bx2y = (const float*)d_in[9];
    float* Y = (float*)d_out;

    char*     ws    = (char*)d_ws;
    float*    c_buf = (float*)(ws + OFF_CBUF);
    uint32_t* initT = (uint32_t*)(ws + OFF_INIT);
    const _Float16* Mf = (const _Float16*)(ws + OFF_M);
    int*      done  = (int*)(ws + OFF_CNT);

    k_scanM <<<256 + CCH*NB_, 128, 0, stream>>>(U, bx2y, lr, li, B, mult, Wx2y,
                                                ws, c_buf, Y);
    k_pc    <<<CCH*8, 256, 0, stream>>>(y0, Wy2x, by2x, lr, li, c_buf, Mf,
                                        initT, Y, done);
}

// Round 3
// 102.263 us; speedup vs baseline: 1.8071x; 1.8071x over previous
//
#include <hip/hip_runtime.h>
#include <math.h>

#define T_   2048
#define NB_  64
#define NU_  8
#define NY_  8
#define NH_  256
#define H2_  128
#define CCH  64      // number of chunks
#define LCH  32      // chunk length = T_/CCH

static const float PI_HALF = 1.5707963267948966f;

typedef _Float16 half8  __attribute__((ext_vector_type(8)));
typedef __fp16   fp16x2 __attribute__((ext_vector_type(2)));
typedef float    f32x4  __attribute__((ext_vector_type(4)));

// ws layout (bytes):
//   M     u32[256][128]                  @ 16384    128 KB
//   c_buf f32[k][b][pair][2]             @ 147456   4 MB
//   initT u32[k][b][128]                 @ 4341760  2 MB
#define OFF_M     16384
#define OFF_CBUF  147456
#define OFF_INIT  4341760

// ---------------- kernel 1: M-precompute blocks + scan/projection blocks -----
// bi <  256 : one row of M (R = bi), 128 threads = 128 pair-columns.
// bi >= 256 : scan block for (k, b) = ((bi-256)>>6, (bi-256)&63).
__global__ __launch_bounds__(128) void k_scanM(
    const float* __restrict__ U, const float* __restrict__ bx2y,
    const float* __restrict__ lr, const float* __restrict__ li,
    const float* __restrict__ B, const float* __restrict__ mult,
    const float* __restrict__ Wx2y,
    char* __restrict__ ws, float* __restrict__ c_buf,
    float* __restrict__ Y)
{
    const int bi  = blockIdx.x;
    const int tid = threadIdx.x;

    if (bi < 256) {
        // ---- M[R = dlt*8+y][m] row, one thread per pair-column ----
        uint32_t* M32 = (uint32_t*)(ws + OFF_M);
        const int R = bi, dlt = R >> 3, y = R & 7;
        const int h = tid;
        const float e = (float)(dlt + 1);
        float r  = expf(-e * fabsf(lr[h]));
        float an = e * PI_HALF * li[h];
        float c = r * cosf(an), sn = r * sinf(an);
        float W1 = Wx2y[y*NH_ + h];
        float W2 = Wx2y[y*NH_ + h + H2_];
        float Mre = fmaf(W1, c,  W2 * sn);
        float Mim = fmaf(W2, c, -W1 * sn);
        union { fp16x2 h2; uint32_t u32; } pk;
        pk.h2 = __builtin_amdgcn_cvt_pkrtz(Mre, Mim);
        M32[R*128 + h] = pk.u32;
        return;
    }

    // ---- scan + K-split MFMA projection ----
    const int kb  = bi - 256;
    const int k   = kb >> 6;
    const int b   = kb & 63;
    const int h   = tid;
    const int w   = tid >> 6;
    const int l   = tid & 63;
    const int row = l & 15;
    const int kg  = (l >> 4) & 3;

    float4 lam;
    {
        float a_ = fabsf(lr[h]);
        float r_ = expf(-a_);
        float th = PI_HALF * li[h];
        float re = r_ * cosf(th), im = r_ * sinf(th);
        lam = make_float4(re, im, -im, re);
    }
    float B1[NU_], B2[NU_];
    {
        float s1 = expf(mult[h]), s2 = expf(mult[h + H2_]);
        const float4* bp1 = (const float4*)(B + h*NU_);
        const float4* bp2 = (const float4*)(B + (h + H2_)*NU_);
        float4 a0 = bp1[0], a1 = bp1[1], a2 = bp2[0], a3 = bp2[1];
        B1[0]=a0.x*s1; B1[1]=a0.y*s1; B1[2]=a0.z*s1; B1[3]=a0.w*s1;
        B1[4]=a1.x*s1; B1[5]=a1.y*s1; B1[6]=a1.z*s1; B1[7]=a1.w*s1;
        B2[0]=a2.x*s2; B2[1]=a2.y*s2; B2[2]=a2.z*s2; B2[3]=a2.w*s2;
        B2[4]=a3.x*s2; B2[5]=a3.y*s2; B2[6]=a3.z*s2; B2[7]=a3.w*s2;
    }
    half8 wf[4];
    #pragma unroll
    for (int q2 = 0; q2 < 4; q2++) {
        const int q = 4*w + q2;
        union { uint32_t u[4]; half8 h8; } fu;
        if (row < 8) {
            const float4 wa = *(const float4*)(Wx2y + row*NH_ + q*16 + kg*4);
            const float4 wb = *(const float4*)(Wx2y + row*NH_ + q*16 + kg*4 + H2_);
            union { fp16x2 h2; uint32_t u32; } p;
            p.h2 = __builtin_amdgcn_cvt_pkrtz(wa.x, wb.x); fu.u[0] = p.u32;
            p.h2 = __builtin_amdgcn_cvt_pkrtz(wa.y, wb.y); fu.u[1] = p.u32;
            p.h2 = __builtin_amdgcn_cvt_pkrtz(wa.z, wb.z); fu.u[2] = p.u32;
            p.h2 = __builtin_amdgcn_cvt_pkrtz(wa.w, wb.w); fu.u[3] = p.u32;
        } else {
            fu.u[0]=0; fu.u[1]=0; fu.u[2]=0; fu.u[3]=0;
        }
        wf[q2] = fu.h8;
    }
    const float bias = bx2y[tid & 7];

    __shared__ float    uS[LCH*NU_];    // 1 KB
    __shared__ _Float16 xS[16*256];     // 8 KB
    __shared__ float    pS[4*132];
    uint32_t* xS32 = (uint32_t*)xS;

    if (tid < 64) {
        ((float4*)uS)[tid] =
            *(const float4*)(U + ((size_t)(k*LCH + (tid>>1))*NB_ + b)*NU_ + (tid&1)*4);
    }
    __syncthreads();

    float x1 = 0.f, x2 = 0.f;
    const int g = h >> 2;

    for (int s = 0; s < 2; s++) {
        #pragma unroll 4
        for (int t16 = 0; t16 < 16; t16++) {
            const int t = s*16 + t16;
            float4 u0 = ((const float4*)uS)[2*t+0];
            float4 u1 = ((const float4*)uS)[2*t+1];
            float u[NU_] = {u0.x,u0.y,u0.z,u0.w,u1.x,u1.y,u1.z,u1.w};
            float bu1=0.f, bu2=0.f;
            #pragma unroll
            for (int i = 0; i < NU_; i++) {
                bu1 = fmaf(u[i], B1[i], bu1);
                bu2 = fmaf(u[i], B2[i], bu2);
            }
            float n1 = fmaf(lam.x, x1, fmaf(lam.z, x2, bu1));
            float n2 = fmaf(lam.y, x1, fmaf(lam.w, x2, bu2));
            x1 = n1; x2 = n2;

            union { fp16x2 h2; uint32_t u32; } pk;
            pk.h2 = __builtin_amdgcn_cvt_pkrtz(x1, x2);
            xS32[t16*128 + ((g ^ t16) & 31)*4 + (h & 3)] = pk.u32;
        }
        __syncthreads();

        f32x4 acc = {0.f,0.f,0.f,0.f};
        #pragma unroll
        for (int q2 = 0; q2 < 4; q2++) {
            const int q = 4*w + q2;
            const int p = ((q << 2) + kg) ^ row;
            const half8* ap = (const half8*)(xS + (row << 8) + (p << 3));
            acc = __builtin_amdgcn_mfma_f32_16x16x32_f16(*ap, wf[q2], acc, 0, 0, 0);
        }
        #pragma unroll
        for (int r = 0; r < 4; r++) pS[r*132 + w*64 + l] = acc[r];
        __syncthreads();

        {
            const int t  = tid >> 3, y = tid & 7;
            const int ls = ((t >> 2) << 4) + y;
            const int rg = t & 3;
            float sum = pS[rg*132 + ls] + pS[rg*132 + 64 + ls];
            Y[((size_t)(k*LCH + s*16 + t)*NB_ + b)*NY_ + y] = sum + bias;
        }
    }

    *(float2*)(c_buf + (size_t)(k*NB_ + b)*(H2_*2) + 2*h) = make_float2(x1, x2);
}

// ---------------- kernel 2: segmented chunk prefix -> f16 transposed inits ---
// 256 blocks x 256 threads. Thread = (chain, seg): chain=(b,h) walks 8 chunks.
// Serial depth 64 -> 8 (pass1) + 7 (combine) + 8 (pass2). Math verified
// (round 2: passed with absmax identical to sequential version).
__global__ __launch_bounds__(256) void k_prefix(
    const float* __restrict__ y0, const float* __restrict__ Wy2x,
    const float* __restrict__ by2x,
    const float* __restrict__ lr, const float* __restrict__ li,
    const float* __restrict__ c_buf, uint32_t* __restrict__ initT)
{
    const int bi  = blockIdx.x;
    const int tid = threadIdx.x;

    __shared__ float2 Pseg[32][8];

    const int chain = (bi << 5) + (tid >> 3);   // 0..8191 = (b,h)
    const int seg   = tid & 7;                  // 0..7
    const int b = chain >> 7, h = chain & 127;

    const float a_  = fabsf(lr[h]);
    const float liv = li[h];
    const float rL  = expf(-(float)LCH * a_);
    const float thL = (float)LCH * PI_HALF * liv;
    const float reL = rL * cosf(thL), imL = rL * sinf(thL);
    const float r8  = expf(-(float)(8*LCH) * a_);
    const float th8 = (float)(8*LCH) * PI_HALF * liv;
    const float re8 = r8 * cosf(th8), im8 = r8 * sinf(th8);

    // pass 1: zero-init partial over this segment's 8 chunks
    float p1 = 0.f, p2 = 0.f;
    #pragma unroll
    for (int i = 0; i < 8; i++) {
        const int k = (seg << 3) + i;
        float2 c = *(const float2*)(c_buf + (size_t)k*16384 + b*256 + 2*h);
        float n1 = fmaf(reL, p1, fmaf(-imL, p2, c.x));
        float n2 = fmaf(imL, p1, fmaf( reL, p2, c.y));
        p1 = n1; p2 = n2;
    }
    Pseg[tid >> 3][seg] = make_float2(p1, p2);

    // true init x0 (redundant per segment-thread; 16 FMAs)
    float x1 = by2x[h], x2 = by2x[h + H2_];
    #pragma unroll
    for (int y = 0; y < NY_; y++) {
        float yy = y0[b*NY_ + y];
        x1 = fmaf(yy, Wy2x[h*NY_ + y],        x1);
        x2 = fmaf(yy, Wy2x[(h+H2_)*NY_ + y],  x2);
    }
    __syncthreads();

    // combine: apply A^(8L) carry across earlier segments
    #pragma unroll
    for (int j = 0; j < 7; j++) {
        if (j < seg) {
            float2 Pj = Pseg[tid >> 3][j];
            float n1 = fmaf(re8, x1, fmaf(-im8, x2, Pj.x));
            float n2 = fmaf(im8, x1, fmaf( re8, x2, Pj.y));
            x1 = n1; x2 = n2;
        }
    }

    // pass 2: re-walk 8 chunks from true segment-start state
    #pragma unroll
    for (int i = 0; i < 8; i++) {
        const int k = (seg << 3) + i;
        union { fp16x2 hh; uint32_t u32; } pk;
        pk.hh = __builtin_amdgcn_cvt_pkrtz(x1, x2);
        initT[(size_t)k*8192 + b*128 + h] = pk.u32;
        float2 c = *(const float2*)(c_buf + (size_t)k*16384 + b*256 + 2*h);
        float n1 = fmaf(reL, x1, fmaf(-imL, x2, c.x));
        float n2 = fmaf(imL, x1, fmaf( reL, x2, c.y));
        x1 = n1; x2 = n2;
    }
}

// ---------------- kernel 3: correction GEMM, Y += M @ init_k -----------------
// 512 blocks = (k, b-half, R-tile-group); 256 threads = 4 waves, 1 R-tile/wave.
__global__ __launch_bounds__(256) void k_corr(
    const _Float16* __restrict__ M, const uint32_t* __restrict__ initT,
    float* __restrict__ Y)
{
    const int bi   = blockIdx.x;
    const int k    = bi >> 3;
    const int half = (bi >> 2) & 1;
    const int rtg  = bi & 3;
    const int tid  = threadIdx.x;
    const int w    = tid >> 6, l = tid & 63;
    const int lane16 = l & 15, kg = l >> 4;

    __shared__ _Float16 bS[32*264];
    {
        uint32_t* bS32 = (uint32_t*)bS;
        const int r = tid >> 3, seg = tid & 7;
        const uint32_t* src = initT + (size_t)k*8192 + (half*32 + r)*128 + seg*16;
        uint32_t* dst = bS32 + r*132 + seg*16;
        ((uint4*)dst)[0] = ((const uint4*)src)[0];
        ((uint4*)dst)[1] = ((const uint4*)src)[1];
        ((uint4*)dst)[2] = ((const uint4*)src)[2];
        ((uint4*)dst)[3] = ((const uint4*)src)[3];
    }
    __syncthreads();

    const int R0 = rtg*64 + w*16;
    half8 af[8];
    #pragma unroll
    for (int q = 0; q < 8; q++)
        af[q] = *(const half8*)(M + (size_t)(R0 + lane16)*256 + q*32 + kg*8);

    f32x4 acc0 = {0.f,0.f,0.f,0.f}, acc1 = {0.f,0.f,0.f,0.f};
    #pragma unroll
    for (int q = 0; q < 8; q++) {
        const half8* b0 = (const half8*)(bS + ( 0 + lane16)*264 + q*32 + kg*8);
        const half8* b1 = (const half8*)(bS + (16 + lane16)*264 + q*32 + kg*8);
        acc0 = __builtin_amdgcn_mfma_f32_16x16x32_f16(af[q], *b0, acc0, 0, 0, 0);
        acc1 = __builtin_amdgcn_mfma_f32_16x16x32_f16(af[q], *b1, acc1, 0, 0, 0);
    }

    const int t  = k*LCH + (R0 >> 3) + (kg >> 1);
    const int y0 = (kg & 1) * 4;
    float4* yp0 = (float4*)(Y + ((size_t)t*NB_ + half*32 +  0 + lane16)*NY_ + y0);
    float4* yp1 = (float4*)(Y + ((size_t)t*NB_ + half*32 + 16 + lane16)*NY_ + y0);
    float4 o0 = *yp0, o1 = *yp1;
    o0.x += acc0[0]; o0.y += acc0[1]; o0.z += acc0[2]; o0.w += acc0[3];
    o1.x += acc1[0]; o1.y += acc1[1]; o1.z += acc1[2]; o1.w += acc1[3];
    *yp0 = o0; *yp1 = o1;
}

extern "C" void kernel_launch(void* const* d_in, const int* in_sizes, int n_in,
                              void* d_out, int out_size, void* d_ws, size_t ws_size,
                              hipStream_t stream) {
    const float* y0   = (const float*)d_in[0];
    const float* U    = (const float*)d_in[1];
    const float* lr   = (const float*)d_in[2];
    const float* li   = (const float*)d_in[3];
    const float* B    = (const float*)d_in[4];
    const float* mult = (const float*)d_in[5];
    const float* Wy2x = (const float*)d_in[6];
    const float* by2x = (const float*)d_in[7];
    const float* Wx2y = (const float*)d_in[8];
    const float* bx2y = (const float*)d_in[9];
    float* Y = (float*)d_out;

    char*     ws    = (char*)d_ws;
    float*    c_buf = (float*)(ws + OFF_CBUF);
    uint32_t* initT = (uint32_t*)(ws + OFF_INIT);
    const _Float16* Mf = (const _Float16*)(ws + OFF_M);

    k_scanM <<<256 + CCH*NB_, 128, 0, stream>>>(U, bx2y, lr, li, B, mult, Wx2y,
                                                ws, c_buf, Y);
    k_prefix<<<256, 256, 0, stream>>>(y0, Wy2x, by2x, lr, li, c_buf, initT);
    k_corr  <<<CCH*8, 256, 0, stream>>>(Mf, initT, Y);
}

// Round 4
// 102.019 us; speedup vs baseline: 1.8114x; 1.0024x over previous
//
#include <hip/hip_runtime.h>
#include <math.h>

#define T_   2048
#define NB_  64
#define NU_  8
#define NY_  8
#define NH_  256
#define H2_  128
#define CCH  64      // number of chunks
#define LCH  32      // chunk length = T_/CCH

static const float PI_HALF = 1.5707963267948966f;

typedef _Float16 half8  __attribute__((ext_vector_type(8)));
typedef __fp16   fp16x2 __attribute__((ext_vector_type(2)));
typedef float    f32x4  __attribute__((ext_vector_type(4)));
typedef float    f32x2  __attribute__((ext_vector_type(2)));

#define FMA2(a,b,c) __builtin_elementwise_fma((a),(b),(c))

// ws layout (bytes):
//   M     u32[256][128]                  @ 16384    128 KB
//   c_buf f32[k][b][pair][2]             @ 147456   4 MB
//   initT u32[k][b][128]                 @ 4341760  2 MB
#define OFF_M     16384
#define OFF_CBUF  147456
#define OFF_INIT  4341760

// ---------------- kernel 1: M-precompute blocks + scan/projection blocks -----
// bi <  256 : one row of M (R = bi), 128 threads = 128 pair-columns.
// bi >= 256 : scan block for (k, b) = ((bi-256)>>6, (bi-256)&63).
__global__ __launch_bounds__(128) void k_scanM(
    const float* __restrict__ U, const float* __restrict__ bx2y,
    const float* __restrict__ lr, const float* __restrict__ li,
    const float* __restrict__ B, const float* __restrict__ mult,
    const float* __restrict__ Wx2y,
    char* __restrict__ ws, float* __restrict__ c_buf,
    float* __restrict__ Y)
{
    const int bi  = blockIdx.x;
    const int tid = threadIdx.x;

    if (bi < 256) {
        // ---- M[R = dlt*8+y][m] row, one thread per pair-column ----
        uint32_t* M32 = (uint32_t*)(ws + OFF_M);
        const int R = bi, dlt = R >> 3, y = R & 7;
        const int h = tid;
        const float e = (float)(dlt + 1);
        float r  = expf(-e * fabsf(lr[h]));
        float an = e * PI_HALF * li[h];
        float c = r * cosf(an), sn = r * sinf(an);
        float W1 = Wx2y[y*NH_ + h];
        float W2 = Wx2y[y*NH_ + h + H2_];
        float Mre = fmaf(W1, c,  W2 * sn);
        float Mim = fmaf(W2, c, -W1 * sn);
        union { fp16x2 h2; uint32_t u32; } pk;
        pk.h2 = __builtin_amdgcn_cvt_pkrtz(Mre, Mim);
        M32[R*128 + h] = pk.u32;
        return;
    }

    // ---- scan + K-split MFMA projection ----
    const int kb  = bi - 256;
    const int k   = kb >> 6;
    const int b   = kb & 63;
    const int h   = tid;
    const int w   = tid >> 6;
    const int l   = tid & 63;
    const int row = l & 15;
    const int kg  = (l >> 4) & 3;

    float4 lam;
    {
        float a_ = fabsf(lr[h]);
        float r_ = expf(-a_);
        float th = PI_HALF * li[h];
        float re = r_ * cosf(th), im = r_ * sinf(th);
        lam = make_float4(re, im, -im, re);
    }
    // K-paired packed coefficients: B1p[i] = (B1[2i], B1[2i+1]) etc.
    f32x2 B1p[4], B2p[4];
    {
        float s1 = expf(mult[h]), s2 = expf(mult[h + H2_]);
        const float4* bp1 = (const float4*)(B + h*NU_);
        const float4* bp2 = (const float4*)(B + (h + H2_)*NU_);
        float4 a0 = bp1[0], a1 = bp1[1], a2 = bp2[0], a3 = bp2[1];
        B1p[0] = f32x2{a0.x*s1, a0.y*s1};
        B1p[1] = f32x2{a0.z*s1, a0.w*s1};
        B1p[2] = f32x2{a1.x*s1, a1.y*s1};
        B1p[3] = f32x2{a1.z*s1, a1.w*s1};
        B2p[0] = f32x2{a2.x*s2, a2.y*s2};
        B2p[1] = f32x2{a2.z*s2, a2.w*s2};
        B2p[2] = f32x2{a3.x*s2, a3.y*s2};
        B2p[3] = f32x2{a3.z*s2, a3.w*s2};
    }
    half8 wf[4];
    #pragma unroll
    for (int q2 = 0; q2 < 4; q2++) {
        const int q = 4*w + q2;
        union { uint32_t u[4]; half8 h8; } fu;
        if (row < 8) {
            const float4 wa = *(const float4*)(Wx2y + row*NH_ + q*16 + kg*4);
            const float4 wb = *(const float4*)(Wx2y + row*NH_ + q*16 + kg*4 + H2_);
            union { fp16x2 h2; uint32_t u32; } p;
            p.h2 = __builtin_amdgcn_cvt_pkrtz(wa.x, wb.x); fu.u[0] = p.u32;
            p.h2 = __builtin_amdgcn_cvt_pkrtz(wa.y, wb.y); fu.u[1] = p.u32;
            p.h2 = __builtin_amdgcn_cvt_pkrtz(wa.z, wb.z); fu.u[2] = p.u32;
            p.h2 = __builtin_amdgcn_cvt_pkrtz(wa.w, wb.w); fu.u[3] = p.u32;
        } else {
            fu.u[0]=0; fu.u[1]=0; fu.u[2]=0; fu.u[3]=0;
        }
        wf[q2] = fu.h8;
    }
    const float bias = bx2y[tid & 7];

    __shared__ float    uS[LCH*NU_];    // 1 KB
    __shared__ _Float16 xS[16*256];     // 8 KB
    __shared__ float    pS[4*132];
    uint32_t* xS32 = (uint32_t*)xS;

    if (tid < 64) {
        ((float4*)uS)[tid] =
            *(const float4*)(U + ((size_t)(k*LCH + (tid>>1))*NB_ + b)*NU_ + (tid&1)*4);
    }
    __syncthreads();

    float x1 = 0.f, x2 = 0.f;
    const int g = h >> 2;

    for (int s = 0; s < 2; s++) {
        #pragma unroll 4
        for (int t16 = 0; t16 < 16; t16++) {
            const int t = s*16 + t16;
            union { float4 f4; f32x2 v2[2]; } u0, u1;
            u0.f4 = ((const float4*)uS)[2*t+0];
            u1.f4 = ((const float4*)uS)[2*t+1];

            // K-paired packed dot products (v_pk_fma_f32):
            f32x2 a1 = {0.f, 0.f}, a2 = {0.f, 0.f};
            a1 = FMA2(u0.v2[0], B1p[0], a1);
            a2 = FMA2(u0.v2[0], B2p[0], a2);
            a1 = FMA2(u0.v2[1], B1p[1], a1);
            a2 = FMA2(u0.v2[1], B2p[1], a2);
            a1 = FMA2(u1.v2[0], B1p[2], a1);
            a2 = FMA2(u1.v2[0], B2p[2], a2);
            a1 = FMA2(u1.v2[1], B1p[3], a1);
            a2 = FMA2(u1.v2[1], B2p[3], a2);

            float n1 = fmaf(lam.x, x1, fmaf(lam.z, x2, a1.x + a1.y));
            float n2 = fmaf(lam.y, x1, fmaf(lam.w, x2, a2.x + a2.y));
            x1 = n1; x2 = n2;

            union { fp16x2 h2; uint32_t u32; } pk;
            pk.h2 = __builtin_amdgcn_cvt_pkrtz(x1, x2);
            xS32[t16*128 + ((g ^ t16) & 31)*4 + (h & 3)] = pk.u32;
        }
        __syncthreads();

        f32x4 acc = {0.f,0.f,0.f,0.f};
        #pragma unroll
        for (int q2 = 0; q2 < 4; q2++) {
            const int q = 4*w + q2;
            const int p = ((q << 2) + kg) ^ row;
            const half8* ap = (const half8*)(xS + (row << 8) + (p << 3));
            acc = __builtin_amdgcn_mfma_f32_16x16x32_f16(*ap, wf[q2], acc, 0, 0, 0);
        }
        #pragma unroll
        for (int r = 0; r < 4; r++) pS[r*132 + w*64 + l] = acc[r];
        __syncthreads();

        {
            const int t  = tid >> 3, y = tid & 7;
            const int ls = ((t >> 2) << 4) + y;
            const int rg = t & 3;
            float sum = pS[rg*132 + ls] + pS[rg*132 + 64 + ls];
            Y[((size_t)(k*LCH + s*16 + t)*NB_ + b)*NY_ + y] = sum + bias;
        }
    }

    *(float2*)(c_buf + (size_t)(k*NB_ + b)*(H2_*2) + 2*h) = make_float2(x1, x2);
}

// ---------------- kernel 2: segmented chunk prefix -> f16 transposed inits ---
// 256 blocks x 256 threads. Thread = (chain, seg): chain=(b,h) walks 8 chunks.
__global__ __launch_bounds__(256) void k_prefix(
    const float* __restrict__ y0, const float* __restrict__ Wy2x,
    const float* __restrict__ by2x,
    const float* __restrict__ lr, const float* __restrict__ li,
    const float* __restrict__ c_buf, uint32_t* __restrict__ initT)
{
    const int bi  = blockIdx.x;
    const int tid = threadIdx.x;

    __shared__ float2 Pseg[32][8];

    const int chain = (bi << 5) + (tid >> 3);   // 0..8191 = (b,h)
    const int seg   = tid & 7;                  // 0..7
    const int b = chain >> 7, h = chain & 127;

    const float a_  = fabsf(lr[h]);
    const float liv = li[h];
    const float rL  = expf(-(float)LCH * a_);
    const float thL = (float)LCH * PI_HALF * liv;
    const float reL = rL * cosf(thL), imL = rL * sinf(thL);
    const float r8  = expf(-(float)(8*LCH) * a_);
    const float th8 = (float)(8*LCH) * PI_HALF * liv;
    const float re8 = r8 * cosf(th8), im8 = r8 * sinf(th8);

    // pass 1: zero-init partial over this segment's 8 chunks
    float p1 = 0.f, p2 = 0.f;
    #pragma unroll
    for (int i = 0; i < 8; i++) {
        const int k = (seg << 3) + i;
        float2 c = *(const float2*)(c_buf + (size_t)k*16384 + b*256 + 2*h);
        float n1 = fmaf(reL, p1, fmaf(-imL, p2, c.x));
        float n2 = fmaf(imL, p1, fmaf( reL, p2, c.y));
        p1 = n1; p2 = n2;
    }
    Pseg[tid >> 3][seg] = make_float2(p1, p2);

    // true init x0 (redundant per segment-thread; 16 FMAs)
    float x1 = by2x[h], x2 = by2x[h + H2_];
    #pragma unroll
    for (int y = 0; y < NY_; y++) {
        float yy = y0[b*NY_ + y];
        x1 = fmaf(yy, Wy2x[h*NY_ + y],        x1);
        x2 = fmaf(yy, Wy2x[(h+H2_)*NY_ + y],  x2);
    }
    __syncthreads();

    // combine: apply A^(8L) carry across earlier segments
    #pragma unroll
    for (int j = 0; j < 7; j++) {
        if (j < seg) {
            float2 Pj = Pseg[tid >> 3][j];
            float n1 = fmaf(re8, x1, fmaf(-im8, x2, Pj.x));
            float n2 = fmaf(im8, x1, fmaf( re8, x2, Pj.y));
            x1 = n1; x2 = n2;
        }
    }

    // pass 2: re-walk 8 chunks from true segment-start state
    #pragma unroll
    for (int i = 0; i < 8; i++) {
        const int k = (seg << 3) + i;
        union { fp16x2 hh; uint32_t u32; } pk;
        pk.hh = __builtin_amdgcn_cvt_pkrtz(x1, x2);
        initT[(size_t)k*8192 + b*128 + h] = pk.u32;
        float2 c = *(const float2*)(c_buf + (size_t)k*16384 + b*256 + 2*h);
        float n1 = fmaf(reL, x1, fmaf(-imL, x2, c.x));
        float n2 = fmaf(imL, x1, fmaf( reL, x2, c.y));
        x1 = n1; x2 = n2;
    }
}

// ---------------- kernel 3: correction GEMM, Y += M @ init_k -----------------
// 512 blocks = (k, b-half, R-tile-group); 256 threads = 4 waves, 1 R-tile/wave.
__global__ __launch_bounds__(256) void k_corr(
    const _Float16* __restrict__ M, const uint32_t* __restrict__ initT,
    float* __restrict__ Y)
{
    const int bi   = blockIdx.x;
    const int k    = bi >> 3;
    const int half = (bi >> 2) & 1;
    const int rtg  = bi & 3;
    const int tid  = threadIdx.x;
    const int w    = tid >> 6, l = tid & 63;
    const int lane16 = l & 15, kg = l >> 4;

    __shared__ _Float16 bS[32*264];
    {
        uint32_t* bS32 = (uint32_t*)bS;
        const int r = tid >> 3, seg = tid & 7;
        const uint32_t* src = initT + (size_t)k*8192 + (half*32 + r)*128 + seg*16;
        uint32_t* dst = bS32 + r*132 + seg*16;
        ((uint4*)dst)[0] = ((const uint4*)src)[0];
        ((uint4*)dst)[1] = ((const uint4*)src)[1];
        ((uint4*)dst)[2] = ((const uint4*)src)[2];
        ((uint4*)dst)[3] = ((const uint4*)src)[3];
    }
    __syncthreads();

    const int R0 = rtg*64 + w*16;
    half8 af[8];
    #pragma unroll
    for (int q = 0; q < 8; q++)
        af[q] = *(const half8*)(M + (size_t)(R0 + lane16)*256 + q*32 + kg*8);

    f32x4 acc0 = {0.f,0.f,0.f,0.f}, acc1 = {0.f,0.f,0.f,0.f};
    #pragma unroll
    for (int q = 0; q < 8; q++) {
        const half8* b0 = (const half8*)(bS + ( 0 + lane16)*264 + q*32 + kg*8);
        const half8* b1 = (const half8*)(bS + (16 + lane16)*264 + q*32 + kg*8);
        acc0 = __builtin_amdgcn_mfma_f32_16x16x32_f16(af[q], *b0, acc0, 0, 0, 0);
        acc1 = __builtin_amdgcn_mfma_f32_16x16x32_f16(af[q], *b1, acc1, 0, 0, 0);
    }

    const int t  = k*LCH + (R0 >> 3) + (kg >> 1);
    const int y0 = (kg & 1) * 4;
    float4* yp0 = (float4*)(Y + ((size_t)t*NB_ + half*32 +  0 + lane16)*NY_ + y0);
    float4* yp1 = (float4*)(Y + ((size_t)t*NB_ + half*32 + 16 + lane16)*NY_ + y0);
    float4 o0 = *yp0, o1 = *yp1;
    o0.x += acc0[0]; o0.y += acc0[1]; o0.z += acc0[2]; o0.w += acc0[3];
    o1.x += acc1[0]; o1.y += acc1[1]; o1.z += acc1[2]; o1.w += acc1[3];
    *yp0 = o0; *yp1 = o1;
}

extern "C" void kernel_launch(void* const* d_in, const int* in_sizes, int n_in,
                              void* d_out, int out_size, void* d_ws, size_t ws_size,
                              hipStream_t stream) {
    const float* y0   = (const float*)d_in[0];
    const float* U    = (const float*)d_in[1];
    const float* lr   = (const float*)d_in[2];
    const float* li   = (const float*)d_in[3];
    const float* B    = (const float*)d_in[4];
    const float* mult = (const float*)d_in[5];
    const float* Wy2x = (const float*)d_in[6];
    const float* by2x = (const float*)d_in[7];
    const float* Wx2y = (const float*)d_in[8];
    const float* bx2y = (const float*)d_in[9];
    float* Y = (float*)d_out;

    char*     ws    = (char*)d_ws;
    float*    c_buf = (float*)(ws + OFF_CBUF);
    uint32_t* initT = (uint32_t*)(ws + OFF_INIT);
    const _Float16* Mf = (const _Float16*)(ws + OFF_M);

    k_scanM <<<256 + CCH*NB_, 128, 0, stream>>>(U, bx2y, lr, li, B, mult, Wx2y,
                                                ws, c_buf, Y);
    k_prefix<<<256, 256, 0, stream>>>(y0, Wy2x, by2x, lr, li, c_buf, initT);
    k_corr  <<<CCH*8, 256, 0, stream>>>(Mf, initT, Y);
}